// Round 12
// baseline (812.622 us; speedup 1.0000x reference)
//
#include <hip/hip_runtime.h>

// ---------- types ----------
typedef __bf16 vbf8 __attribute__((ext_vector_type(8)));
typedef unsigned short us8 __attribute__((ext_vector_type(8)));
typedef float f32x4 __attribute__((ext_vector_type(4)));
typedef float f32x4u __attribute__((ext_vector_type(4), aligned(4)));

// ---------- band-case helpers ----------
__device__ __forceinline__ int caseof(int h, int H, int e) {
  if (h < 0 || h >= H) return -1;           // EDGE
  if (h < e) return h;
  if (h >= H - e) return h - (H - 1) + 2 * e;
  return e;
}
__device__ __forceinline__ int repof(int i, int H, int eo) {
  return (i <= eo) ? i : H - 1 - 2 * eo + i;
}

__device__ __forceinline__ vbf8 max8(vbf8 a, vbf8 b) {
  us8 ua = __builtin_bit_cast(us8, a), ub = __builtin_bit_cast(us8, b);
  us8 o;
#pragma unroll
  for (int e = 0; e < 8; ++e) o[e] = ua[e] > ub[e] ? ua[e] : ub[e];
  return __builtin_bit_cast(vbf8, o);
}

// ---------------------------------------------------------------------------
// pillar + convw kernel. Blocks 0..431 first transpose conv weights
// (HWIO [tap][ci][co] f32 -> wT [tap][co][ci] bf16); wT is consumed only by
// the NEXT kernel, so no intra-kernel dependency. All 6000 blocks then run
// the pillar feature net (MFMA weight fragments built inline per block).
// ---------------------------------------------------------------------------
__global__ __launch_bounds__(256) void pillar_kernel(
    const float* __restrict__ pil, const int* __restrict__ npt,
    const float* __restrict__ w1, const float* __restrict__ b1,
    const float* __restrict__ s1, const float* __restrict__ t1,
    const float* __restrict__ w2, const float* __restrict__ b2,
    const float* __restrict__ s2, const float* __restrict__ t2,
    const float* __restrict__ k1, const float* __restrict__ k2,
    const float* __restrict__ k3, const float* __restrict__ k4,
    const float* __restrict__ k5, const float* __restrict__ k6,
    const float* __restrict__ kh, __bf16* __restrict__ wT,
    float* __restrict__ partial, int* __restrict__ pcnt)
{
  __shared__ float tile[64][65];
  __shared__ float redf[4][64];
  __shared__ int redc[4];
  const int tid = threadIdx.x;
  const int wv = tid >> 6, lane = tid & 63;
  const int s = lane & 15, g = lane >> 4;

  if (blockIdx.x < 432) {
    // ---- convw duty ----
    const int tCI[7]    = {64, 64, 64, 128, 128, 256, 256};
    const int tCO[7]    = {64, 64, 128, 128, 256, 256, 256};
    const int tOFF[7]   = {0, 36864, 73728, 147456, 294912, 589824, 1179648};
    const int tTILES[7] = {9, 9, 18, 36, 72, 144, 144};
    int bid = blockIdx.x;
    int ti = 0, acc = 0;
    while (ti < 6 && bid >= acc + tTILES[ti]) { acc += tTILES[ti]; ++ti; }
    int lt = bid - acc;
    int CI = tCI[ti], CO = tCO[ti];
    const float* src;
    if (ti == 0) src = k1; else if (ti == 1) src = k2; else if (ti == 2) src = k3;
    else if (ti == 3) src = k4; else if (ti == 4) src = k5; else if (ti == 5) src = k6;
    else src = kh;
    int cot = CO / 64, tpt = (CI / 64) * cot;
    int tap = lt / tpt; int r2 = lt - tap * tpt;
    int ci0 = (r2 / cot) * 64, co0 = (r2 % cot) * 64;
    const float* sp = src + (size_t)(tap * CI + ci0) * CO + co0;
    int lr = tid >> 6, lc = tid & 63;
#pragma unroll
    for (int rr = 0; rr < 64; rr += 4)
      tile[rr + lr][lc] = sp[(size_t)(rr + lr) * CO + lc];
    __syncthreads();
    __bf16* dst = wT + tOFF[ti] + ((size_t)tap * CO + co0) * CI + ci0;
#pragma unroll
    for (int rr = 0; rr < 64; rr += 4)
      dst[(size_t)(rr + lr) * CI + lc] = (__bf16)tile[lc][rr + lr];
  }

  // ---- inline weight-fragment setup (identical math in every block) ----
  vbf8 w1f[4], w2f0[4], w2f1[4];
  float be2[4];
#pragma unroll
  for (int m = 0; m < 4; ++m) {
    int c = 32 * (m & 1) + 8 * (s >> 2) + 4 * (m >> 1) + (s & 3);
#pragma unroll
    for (int e = 0; e < 8; ++e) {
      int k = g * 8 + e;
      float v = 0.f;
      if (k < 9)       v = w1[k * 64 + c] * s1[c];
      else if (k == 9) v = fmaf(b1[c], s1[c], t1[c]);
      w1f[m][e] = (__bf16)v;
    }
    int co = s + 16 * m;
#pragma unroll
    for (int e = 0; e < 8; ++e) {
      int k = g * 8 + e;
      w2f0[m][e] = (__bf16)(w2[k * 64 + co] * s2[co]);
      w2f1[m][e] = (__bf16)(w2[(32 + k) * 64 + co] * s2[co]);
    }
    be2[m] = fmaf(b2[co], s2[co], t2[co]);
  }

  const int wid = blockIdx.x * 4 + wv;       // 0..23999
  const int b = wid / 6000;
  const int p0 = (wid - b * 6000) * 2;

  float fsum[4] = {0.f, 0.f, 0.f, 0.f};
  int cnt = 0;

  for (int i = 0; i < 2; ++i) {
    int pidx = b * 12000 + p0 + i;
    int np = npt[pidx];
    if (np <= 0) continue;     // wave-uniform
    ++cnt;
    float feat[4][4];
#pragma unroll
    for (int n = 0; n < 4; ++n)
#pragma unroll
      for (int r = 0; r < 4; ++r) feat[n][r] = 0.f;

    int ngrp = (np + 15) >> 4;
    const float* pbase = pil + (size_t)pidx * 900;
    const float* pp0 = pbase + s * 9;
    f32x4u lo = *(const f32x4u*)pp0;
    f32x4u hi = *(const f32x4u*)(pp0 + 4);
    float v8 = pp0[8];
    for (int grp = 0; grp < ngrp; ++grp) {
      int g2 = min(grp + 1, ngrp - 1);
      int ptn = min(g2 * 16 + s, 99);
      const float* ppn = pbase + ptn * 9;
      f32x4u nlo = *(const f32x4u*)ppn;
      f32x4u nhi = *(const f32x4u*)(ppn + 4);
      float nv8 = ppn[8];

      vbf8 b1f;
      b1f[0] = (__bf16)(g == 0 ? lo[0] : (g == 1 ? v8 : 0.f));
      b1f[1] = (__bf16)(g == 0 ? lo[1] : (g == 1 ? 1.0f : 0.f));
      b1f[2] = (__bf16)(g == 0 ? lo[2] : 0.f);
      b1f[3] = (__bf16)(g == 0 ? lo[3] : 0.f);
      b1f[4] = (__bf16)(g == 0 ? hi[0] : 0.f);
      b1f[5] = (__bf16)(g == 0 ? hi[1] : 0.f);
      b1f[6] = (__bf16)(g == 0 ? hi[2] : 0.f);
      b1f[7] = (__bf16)(g == 0 ? hi[3] : 0.f);

      const f32x4 z = {0.f, 0.f, 0.f, 0.f};
      f32x4 d1[4];
#pragma unroll
      for (int m = 0; m < 4; ++m)
        d1[m] = __builtin_amdgcn_mfma_f32_16x16x32_bf16(w1f[m], b1f, z, 0, 0, 0);

      vbf8 a2f0, a2f1;
#pragma unroll
      for (int r = 0; r < 4; ++r) {
        a2f0[r]     = (__bf16)fmaxf(d1[0][r], 0.f);
        a2f1[r]     = (__bf16)fmaxf(d1[1][r], 0.f);
        a2f0[4 + r] = (__bf16)fmaxf(d1[2][r], 0.f);
        a2f1[4 + r] = (__bf16)fmaxf(d1[3][r], 0.f);
      }

      f32x4 d2[4];
#pragma unroll
      for (int n = 0; n < 4; ++n) {
        f32x4 cb = {be2[n], be2[n], be2[n], be2[n]};
        d2[n] = __builtin_amdgcn_mfma_f32_16x16x32_bf16(a2f0, w2f0[n], cb, 0, 0, 0);
        d2[n] = __builtin_amdgcn_mfma_f32_16x16x32_bf16(a2f1, w2f1[n], d2[n], 0, 0, 0);
      }
      if (((grp + 1) << 4) <= np) {
#pragma unroll
        for (int n = 0; n < 4; ++n)
#pragma unroll
          for (int r = 0; r < 4; ++r) feat[n][r] = fmaxf(feat[n][r], d2[n][r]);
      } else {
#pragma unroll
        for (int n = 0; n < 4; ++n)
#pragma unroll
          for (int r = 0; r < 4; ++r) {
            float vv = (grp * 16 + 4 * g + r < np) ? d2[n][r] : 0.f;
            feat[n][r] = fmaxf(feat[n][r], vv);
          }
      }
      lo = nlo; hi = nhi; v8 = nv8;
    }
#pragma unroll
    for (int n = 0; n < 4; ++n) {
      float m = fmaxf(fmaxf(feat[n][0], feat[n][1]), fmaxf(feat[n][2], feat[n][3]));
      m = fmaxf(m, __shfl_xor(m, 16));
      m = fmaxf(m, __shfl_xor(m, 32));
      fsum[n] += m;
    }
  }
  if (g == 0) {
#pragma unroll
    for (int n = 0; n < 4; ++n) redf[wv][s + 16 * n] = fsum[n];
  }
  if (lane == 0) redc[wv] = cnt;
  __syncthreads();
  if (tid < 64) {
    float tot = redf[0][tid] + redf[1][tid] + redf[2][tid] + redf[3][tid];
    partial[blockIdx.x * 64 + tid] = tot;
    if (tid == 0) pcnt[blockIdx.x] = redc[0] + redc[1] + redc[2] + redc[3];
  }
}

// ---------------------------------------------------------------------------
// Per-batch case-grid conv over LDS buffers (no batch dim, no grid sync).
// If POOL: input is the pre-pool grid at size 2H with band EIN; 2x2 max
// fused into A-loads. m range [m0, m0+mcount) supports chunked output.
// ---------------------------------------------------------------------------
template <int CI, int CO, int H, int EIN, bool POOL, bool HAS_BN, bool OUT_F32>
__device__ __forceinline__ void caseconvL(
    int wv, int lane, const __bf16* __restrict__ xin,
    const __bf16* __restrict__ wt,
    const float* __restrict__ cb, const float* __restrict__ cs,
    const float* __restrict__ ct,
    __bf16* __restrict__ yout, float* __restrict__ yf32,
    const __bf16* __restrict__ zpad, int m0, int mcount)
{
  constexpr int EV   = POOL ? (EIN + 1) / 2 : EIN;
  constexpr int EOUT = EV + 1;
  constexpr int NBI  = 2 * EIN + 1;
  constexpr int HX   = POOL ? 2 * H : H;
  constexpr int NBO  = 2 * EOUT + 1;
  constexpr int NT   = CO / 16;
  constexpr int KC   = CI / 32;
  const int s = lane & 15, g = lane >> 4;
  const int MT = (mcount + 31) >> 5;
  for (int wid = wv; wid < MT * NT; wid += 16) {
    const int nt = wid % NT, mt = wid / NT;
    int reph[2], repw[2];
#pragma unroll
    for (int mf = 0; mf < 2; ++mf) {
      int m = m0 + mt * 32 + mf * 16 + s;
      if (m >= m0 + mcount) m = m0 + mcount - 1;
      int bh = m / NBO, bw = m % NBO;
      reph[mf] = repof(bh, H, EOUT); repw[mf] = repof(bw, H, EOUT);
    }
    f32x4 acc0 = {0.f, 0.f, 0.f, 0.f}, acc1 = {0.f, 0.f, 0.f, 0.f};
#pragma unroll
    for (int tap = 0; tap < 9; ++tap) {
      const int dh = tap / 3, dw = tap % 3;
      const __bf16* wtap = wt + ((size_t)tap * CO + nt * 16) * CI + 8 * g;
      const __bf16* base[2][POOL ? 4 : 1];
#pragma unroll
      for (int mf = 0; mf < 2; ++mf) {
        int vh = reph[mf] + dh - 1, vw = repw[mf] + dw - 1;
        if constexpr (POOL) {
          bool valid = (vh >= 0) && (vh < H) && (vw >= 0) && (vw < H);
          int h0 = 0, h1 = 0, w0 = 0, w1 = 0;
          if (valid) {
            h0 = caseof(2 * vh, HX, EIN); h1 = caseof(2 * vh + 1, HX, EIN);
            w0 = caseof(2 * vw, HX, EIN); w1 = caseof(2 * vw + 1, HX, EIN);
          }
          base[mf][0] = valid ? xin + (size_t)(h0 * NBI + w0) * CI : zpad;
          base[mf][1] = valid ? xin + (size_t)(h0 * NBI + w1) * CI : zpad;
          base[mf][2] = valid ? xin + (size_t)(h1 * NBI + w0) * CI : zpad;
          base[mf][3] = valid ? xin + (size_t)(h1 * NBI + w1) * CI : zpad;
        } else {
          int jh = caseof(vh, H, EIN), jw = caseof(vw, H, EIN);
          bool v = (jh >= 0) && (jw >= 0);
          base[mf][0] = v ? xin + (size_t)(jh * NBI + jw) * CI : zpad;
        }
      }
#pragma unroll
      for (int ck = 0; ck < KC; ++ck) {
        vbf8 a0, a1;
        if constexpr (POOL) {
          a0 = max8(max8(*(const vbf8*)(base[0][0] + ck * 32 + 8 * g),
                         *(const vbf8*)(base[0][1] + ck * 32 + 8 * g)),
                    max8(*(const vbf8*)(base[0][2] + ck * 32 + 8 * g),
                         *(const vbf8*)(base[0][3] + ck * 32 + 8 * g)));
          a1 = max8(max8(*(const vbf8*)(base[1][0] + ck * 32 + 8 * g),
                         *(const vbf8*)(base[1][1] + ck * 32 + 8 * g)),
                    max8(*(const vbf8*)(base[1][2] + ck * 32 + 8 * g),
                         *(const vbf8*)(base[1][3] + ck * 32 + 8 * g)));
        } else {
          a0 = *(const vbf8*)(base[0][0] + ck * 32 + 8 * g);
          a1 = *(const vbf8*)(base[1][0] + ck * 32 + 8 * g);
        }
        vbf8 bb = *(const vbf8*)(wtap + (size_t)s * CI + ck * 32);
        acc0 = __builtin_amdgcn_mfma_f32_16x16x32_bf16(a0, bb, acc0, 0, 0, 0);
        acc1 = __builtin_amdgcn_mfma_f32_16x16x32_bf16(a1, bb, acc1, 0, 0, 0);
      }
    }
    int co = nt * 16 + s;
    float sc, sh;
    if (HAS_BN) { sc = cs[co]; sh = fmaf(cb[co], sc, ct[co]); }
    else        { sc = 1.f;    sh = cb[co]; }
#pragma unroll
    for (int mf = 0; mf < 2; ++mf) {
      f32x4 acc = mf ? acc1 : acc0;
#pragma unroll
      for (int r = 0; r < 4; ++r) {
        int m = m0 + mt * 32 + mf * 16 + 4 * g + r;
        if (m < m0 + mcount) {
          float v = fmaxf(fmaf(acc[r], sc, sh), 0.f);
          if constexpr (OUT_F32) yf32[(size_t)(m - m0) * CO + co] = v;
          else                   yout[(size_t)m * CO + co] = (__bf16)v;
        }
      }
    }
  }
}

// ---------------------------------------------------------------------------
// backbone: 4 blocks (one batch each), entire conv chain in LDS; only
// __syncthreads between layers — zero cross-block dependencies.
// ---------------------------------------------------------------------------
__global__ __launch_bounds__(1024) void backbone_kernel(
    const float* __restrict__ ppart, const int* __restrict__ pcnt,
    const __bf16* wt1, const __bf16* wt2, const __bf16* wt3, const __bf16* wt4,
    const __bf16* wt5, const __bf16* wt6, const __bf16* wth,
    const float* cb1, const float* cs1, const float* ct1,
    const float* cb2, const float* cs2, const float* ct2,
    const float* cb3, const float* cs3, const float* ct3,
    const float* cb4, const float* cs4, const float* ct4,
    const float* cb5, const float* cs5, const float* ct5,
    const float* cb6, const float* cs6, const float* ct6,
    const float* hb1, const float* hk2, const float* hb2,
    float* __restrict__ out)
{
  __shared__ float Af[64 * 256];            // 65,536 B (also X1/X3/X5 as bf16)
  __shared__ __bf16 Bb[81 * 256];           // 41,472 B (X2/X4/X6; int scratch)
  __shared__ __bf16 X0l[64];
  __shared__ __bf16 zpad[256];
  const int tid = threadIdx.x;
  const int wv = tid >> 6, lane = tid & 63;
  const int b = blockIdx.x;

  // ---- mean of valid pillar features -> X0l ----
  {
    int c = tid & 63, q = tid >> 6;
    float sum = 0.f;
    for (int w = q; w < 1500; w += 16) sum += ppart[(b * 1500 + w) * 64 + c];
    int cl = 0;
    for (int w = tid; w < 1500; w += 1024) cl += pcnt[b * 1500 + w];
    Af[tid] = sum;
    int* shi = (int*)Bb;
    shi[tid] = cl;
    __syncthreads();
    for (int o = 512; o > 0; o >>= 1) {
      if (tid < o) shi[tid] += shi[tid + o];
      __syncthreads();
    }
    if (tid < 64) {
      float tot = 0.f;
#pragma unroll
      for (int q2 = 0; q2 < 16; ++q2) tot += Af[q2 * 64 + tid];
      X0l[tid] = (__bf16)(tot / (float)(shi[0] > 0 ? shi[0] : 1));
    }
    if (tid < 256) zpad[tid] = (__bf16)0.f;
    __syncthreads();
  }
  __bf16* A16 = (__bf16*)Af;

  // c1: X0 -> A16 (X1: 3x3, M=9)
  caseconvL<64, 64, 64, 0, false, true, false>(wv, lane, X0l, wt1, cb1, cs1, ct1,
                                               A16, nullptr, zpad, 0, 9);
  __syncthreads();
  // c2: A16 -> Bb (X2: 5x5, M=25)
  caseconvL<64, 64, 64, 1, false, true, false>(wv, lane, A16, wt2, cb2, cs2, ct2,
                                               Bb, nullptr, zpad, 0, 25);
  __syncthreads();
  // c3 (+pool): Bb -> A16 (X3: 5x5, M=25, CO=128)
  caseconvL<64, 128, 32, 2, true, true, false>(wv, lane, Bb, wt3, cb3, cs3, ct3,
                                               A16, nullptr, zpad, 0, 25);
  __syncthreads();
  // c4: A16 -> Bb (X4: 7x7, M=49, CO=128)
  caseconvL<128, 128, 32, 2, false, true, false>(wv, lane, A16, wt4, cb4, cs4, ct4,
                                                 Bb, nullptr, zpad, 0, 49);
  __syncthreads();
  // c5 (+pool): Bb -> A16 (X5: 7x7, M=49, CO=256)
  caseconvL<128, 256, 16, 3, true, true, false>(wv, lane, Bb, wt5, cb5, cs5, ct5,
                                                A16, nullptr, zpad, 0, 49);
  __syncthreads();
  // c6: A16 -> Bb (X6: 9x9, M=81, CO=256)
  caseconvL<256, 256, 16, 3, false, true, false>(wv, lane, A16, wt6, cb6, cs6, ct6,
                                                 Bb, nullptr, zpad, 0, 81);
  __syncthreads();

  // head conv (11x11, M=121) in f32 chunks + fused 1x1 head + scatter
  for (int chunk = 0; chunk < 2; ++chunk) {
    int m0 = chunk * 64, mc = chunk ? 57 : 64;
    caseconvL<256, 256, 16, 4, false, false, true>(wv, lane, Bb, wth, hb1,
                                                   nullptr, nullptr, nullptr,
                                                   Af, zpad, m0, mc);
    __syncthreads();
    for (int t = tid; t < 8370; t += 1024) {
      int ch = t / 837, rc = t % 837;
      int r = rc / 31, c = rc % 31;
      int rr = (r <= 7) ? r : ((r >= 20) ? r - 11 : 7);
      int cc = (c <= 7) ? c : ((c >= 24) ? c - 15 : 7);
      int ph = caseof(rr, 16, 5), pw = caseof(cc, 16, 5);
      int m = ph * 11 + pw;
      if (m >= m0 && m < m0 + mc) {
        const float* xr = Af + (size_t)(m - m0) * 256;
        float a0 = 0.f, a1 = 0.f, a2 = 0.f, a3 = 0.f;
#pragma unroll 4
        for (int ci = 0; ci < 256; ci += 4) {
          float4 in4 = *(const float4*)(xr + ci);
          a0 = fmaf(in4.x, hk2[(ci + 0) * 10 + ch], a0);
          a1 = fmaf(in4.y, hk2[(ci + 1) * 10 + ch], a1);
          a2 = fmaf(in4.z, hk2[(ci + 2) * 10 + ch], a2);
          a3 = fmaf(in4.w, hk2[(ci + 3) * 10 + ch], a3);
        }
        out[((size_t)(b * 10 + ch) * 27 + r) * 31 + c] =
            (a0 + a1) + (a2 + a3) + hb2[ch];
      }
    }
    __syncthreads();
  }
}

// ---------------------------------------------------------------------------
extern "C" void kernel_launch(void* const* d_in, const int* in_sizes, int n_in,
                              void* d_out, int out_size, void* d_ws, size_t ws_size,
                              hipStream_t stream) {
  (void)in_sizes; (void)n_in; (void)out_size; (void)ws_size;
  const float* pillars = (const float*)d_in[0];
  const float* w1 = (const float*)d_in[1];
  const float* b1 = (const float*)d_in[2];
  const float* s1 = (const float*)d_in[3];
  const float* t1 = (const float*)d_in[4];
  const float* w2 = (const float*)d_in[5];
  const float* b2 = (const float*)d_in[6];
  const float* s2 = (const float*)d_in[7];
  const float* t2 = (const float*)d_in[8];
  const float* ck[6], *cbv[6], *csv[6], *ctv[6];
  for (int i = 0; i < 6; ++i) {
    ck[i]  = (const float*)d_in[9 + i * 4];
    cbv[i] = (const float*)d_in[10 + i * 4];
    csv[i] = (const float*)d_in[11 + i * 4];
    ctv[i] = (const float*)d_in[12 + i * 4];
  }
  const float* hk1 = (const float*)d_in[33];
  const float* hb1 = (const float*)d_in[34];
  const float* hk2 = (const float*)d_in[35];
  const float* hb2 = (const float*)d_in[36];
  const int* num_points = (const int*)d_in[37];
  float* out = (float*)d_out;

  // ---- ws layout ----
  char* wsb = (char*)d_ws;
  size_t off = 0;
  auto alloc = [&](size_t n) { char* p = wsb + off; off = (off + n + 255) & ~(size_t)255; return p; };
  float*  ppart = (float*)alloc(1536000);
  int*    pcnt  = (int*)alloc(24000);
  __bf16* wT    = (__bf16*)alloc(3538944);

  __bf16* wt1 = wT + 0;       __bf16* wt2 = wT + 36864;
  __bf16* wt3 = wT + 73728;   __bf16* wt4 = wT + 147456;
  __bf16* wt5 = wT + 294912;  __bf16* wt6 = wT + 589824;
  __bf16* wth = wT + 1179648;

  pillar_kernel<<<6000, 256, 0, stream>>>(
      pillars, num_points, w1, b1, s1, t1, w2, b2, s2, t2,
      ck[0], ck[1], ck[2], ck[3], ck[4], ck[5], hk1, wT, ppart, pcnt);
  backbone_kernel<<<4, 1024, 0, stream>>>(
      ppart, pcnt, wt1, wt2, wt3, wt4, wt5, wt6, wth,
      cbv[0], csv[0], ctv[0], cbv[1], csv[1], ctv[1],
      cbv[2], csv[2], ctv[2], cbv[3], csv[3], ctv[3],
      cbv[4], csv[4], ctv[4], cbv[5], csv[5], ctv[5],
      hb1, hk2, hb2, out);
}

// Round 13
// 489.920 us; speedup vs baseline: 1.6587x; 1.6587x over previous
//
#include <hip/hip_runtime.h>

// ---------- types ----------
typedef __bf16 vbf8 __attribute__((ext_vector_type(8)));
typedef unsigned short us8 __attribute__((ext_vector_type(8)));
typedef float f32x4 __attribute__((ext_vector_type(4)));
typedef float f32x4u __attribute__((ext_vector_type(4), aligned(4)));

// ---------- band-case helpers ----------
__device__ __forceinline__ int caseof(int h, int H, int e) {
  if (h < 0 || h >= H) return -1;           // EDGE
  if (h < e) return h;
  if (h >= H - e) return h - (H - 1) + 2 * e;
  return e;
}
__device__ __forceinline__ int repof(int i, int H, int eo) {
  return (i <= eo) ? i : H - 1 - 2 * eo + i;
}

__device__ __forceinline__ vbf8 max8(vbf8 a, vbf8 b) {
  us8 ua = __builtin_bit_cast(us8, a), ub = __builtin_bit_cast(us8, b);
  us8 o;
#pragma unroll
  for (int e = 0; e < 8; ++e) o[e] = ua[e] > ub[e] ? ua[e] : ub[e];
  return __builtin_bit_cast(vbf8, o);
}

// ---------------------------------------------------------------------------
// pillar + convw kernel. Blocks 0..431 transpose+PACK conv weights into MFMA
// fragment order: wP[tap][nt][ck][lane][8] bf16 (each (tap,nt,ck) = one
// contiguous 1KB wave B-fragment). wP consumed only by the NEXT kernel.
// All 6000 blocks then run the pillar feature net.
// ---------------------------------------------------------------------------
__global__ __launch_bounds__(256) void pillar_kernel(
    const float* __restrict__ pil, const int* __restrict__ npt,
    const float* __restrict__ w1, const float* __restrict__ b1,
    const float* __restrict__ s1, const float* __restrict__ t1,
    const float* __restrict__ w2, const float* __restrict__ b2,
    const float* __restrict__ s2, const float* __restrict__ t2,
    const float* __restrict__ k1, const float* __restrict__ k2,
    const float* __restrict__ k3, const float* __restrict__ k4,
    const float* __restrict__ k5, const float* __restrict__ k6,
    const float* __restrict__ kh, __bf16* __restrict__ wT,
    float* __restrict__ partial, int* __restrict__ pcnt)
{
  __shared__ float tile[64][65];
  __shared__ float redf[4][64];
  __shared__ int redc[4];
  const int tid = threadIdx.x;
  const int wv = tid >> 6, lane = tid & 63;
  const int s = lane & 15, g = lane >> 4;

  if (blockIdx.x < 432) {
    // ---- convw duty: transpose 64x64 tile, then write PACKED layout ----
    const int tCI[7]    = {64, 64, 64, 128, 128, 256, 256};
    const int tCO[7]    = {64, 64, 128, 128, 256, 256, 256};
    const int tOFF[7]   = {0, 36864, 73728, 147456, 294912, 589824, 1179648};
    const int tTILES[7] = {9, 9, 18, 36, 72, 144, 144};
    int bid = blockIdx.x;
    int ti = 0, acc = 0;
    while (ti < 6 && bid >= acc + tTILES[ti]) { acc += tTILES[ti]; ++ti; }
    int lt = bid - acc;
    int CI = tCI[ti], CO = tCO[ti];
    const float* src;
    if (ti == 0) src = k1; else if (ti == 1) src = k2; else if (ti == 2) src = k3;
    else if (ti == 3) src = k4; else if (ti == 4) src = k5; else if (ti == 5) src = k6;
    else src = kh;
    int cot = CO / 64, tpt = (CI / 64) * cot;
    int tap = lt / tpt; int r2 = lt - tap * tpt;
    int ci0 = (r2 / cot) * 64, co0 = (r2 % cot) * 64;
    const float* sp = src + (size_t)(tap * CI + ci0) * CO + co0;
    int lr = tid >> 6, lc = tid & 63;
#pragma unroll
    for (int rr = 0; rr < 64; rr += 4)
      tile[rr + lr][lc] = sp[(size_t)(rr + lr) * CO + lc];
    __syncthreads();
    __bf16* dstL = wT + tOFF[ti];
    int NT = CO >> 4, KCw = CI >> 5;
#pragma unroll
    for (int rr = 0; rr < 64; rr += 4) {
      int co = co0 + rr + lr;
      int ci = ci0 + lc;
      int nt = co >> 4, ss = co & 15;
      int ck = ci >> 5, gg = (ci >> 3) & 3, ee = ci & 7;
      size_t off = ((((size_t)tap * NT + nt) * KCw + ck) * 64 + gg * 16 + ss) * 8 + ee;
      dstL[off] = (__bf16)tile[lc][rr + lr];
    }
  }

  // ---- inline pillar weight-fragment setup ----
  vbf8 w1f[4], w2f0[4], w2f1[4];
  float be2[4];
#pragma unroll
  for (int m = 0; m < 4; ++m) {
    int c = 32 * (m & 1) + 8 * (s >> 2) + 4 * (m >> 1) + (s & 3);
#pragma unroll
    for (int e = 0; e < 8; ++e) {
      int k = g * 8 + e;
      float v = 0.f;
      if (k < 9)       v = w1[k * 64 + c] * s1[c];
      else if (k == 9) v = fmaf(b1[c], s1[c], t1[c]);
      w1f[m][e] = (__bf16)v;
    }
    int co = s + 16 * m;
#pragma unroll
    for (int e = 0; e < 8; ++e) {
      int k = g * 8 + e;
      w2f0[m][e] = (__bf16)(w2[k * 64 + co] * s2[co]);
      w2f1[m][e] = (__bf16)(w2[(32 + k) * 64 + co] * s2[co]);
    }
    be2[m] = fmaf(b2[co], s2[co], t2[co]);
  }

  const int wid = blockIdx.x * 4 + wv;       // 0..23999
  const int b = wid / 6000;
  const int p0 = (wid - b * 6000) * 2;

  float fsum[4] = {0.f, 0.f, 0.f, 0.f};
  int cnt = 0;

  for (int i = 0; i < 2; ++i) {
    int pidx = b * 12000 + p0 + i;
    int np = npt[pidx];
    if (np <= 0) continue;     // wave-uniform
    ++cnt;
    float feat[4][4];
#pragma unroll
    for (int n = 0; n < 4; ++n)
#pragma unroll
      for (int r = 0; r < 4; ++r) feat[n][r] = 0.f;

    int ngrp = (np + 15) >> 4;
    const float* pbase = pil + (size_t)pidx * 900;
    const float* pp0 = pbase + s * 9;
    f32x4u lo = *(const f32x4u*)pp0;
    f32x4u hi = *(const f32x4u*)(pp0 + 4);
    float v8 = pp0[8];
    for (int grp = 0; grp < ngrp; ++grp) {
      int g2 = min(grp + 1, ngrp - 1);
      int ptn = min(g2 * 16 + s, 99);
      const float* ppn = pbase + ptn * 9;
      f32x4u nlo = *(const f32x4u*)ppn;
      f32x4u nhi = *(const f32x4u*)(ppn + 4);
      float nv8 = ppn[8];

      vbf8 b1f;
      b1f[0] = (__bf16)(g == 0 ? lo[0] : (g == 1 ? v8 : 0.f));
      b1f[1] = (__bf16)(g == 0 ? lo[1] : (g == 1 ? 1.0f : 0.f));
      b1f[2] = (__bf16)(g == 0 ? lo[2] : 0.f);
      b1f[3] = (__bf16)(g == 0 ? lo[3] : 0.f);
      b1f[4] = (__bf16)(g == 0 ? hi[0] : 0.f);
      b1f[5] = (__bf16)(g == 0 ? hi[1] : 0.f);
      b1f[6] = (__bf16)(g == 0 ? hi[2] : 0.f);
      b1f[7] = (__bf16)(g == 0 ? hi[3] : 0.f);

      const f32x4 z = {0.f, 0.f, 0.f, 0.f};
      f32x4 d1[4];
#pragma unroll
      for (int m = 0; m < 4; ++m)
        d1[m] = __builtin_amdgcn_mfma_f32_16x16x32_bf16(w1f[m], b1f, z, 0, 0, 0);

      vbf8 a2f0, a2f1;
#pragma unroll
      for (int r = 0; r < 4; ++r) {
        a2f0[r]     = (__bf16)fmaxf(d1[0][r], 0.f);
        a2f1[r]     = (__bf16)fmaxf(d1[1][r], 0.f);
        a2f0[4 + r] = (__bf16)fmaxf(d1[2][r], 0.f);
        a2f1[4 + r] = (__bf16)fmaxf(d1[3][r], 0.f);
      }

      f32x4 d2[4];
#pragma unroll
      for (int n = 0; n < 4; ++n) {
        f32x4 cb = {be2[n], be2[n], be2[n], be2[n]};
        d2[n] = __builtin_amdgcn_mfma_f32_16x16x32_bf16(a2f0, w2f0[n], cb, 0, 0, 0);
        d2[n] = __builtin_amdgcn_mfma_f32_16x16x32_bf16(a2f1, w2f1[n], d2[n], 0, 0, 0);
      }
      if (((grp + 1) << 4) <= np) {
#pragma unroll
        for (int n = 0; n < 4; ++n)
#pragma unroll
          for (int r = 0; r < 4; ++r) feat[n][r] = fmaxf(feat[n][r], d2[n][r]);
      } else {
#pragma unroll
        for (int n = 0; n < 4; ++n)
#pragma unroll
          for (int r = 0; r < 4; ++r) {
            float vv = (grp * 16 + 4 * g + r < np) ? d2[n][r] : 0.f;
            feat[n][r] = fmaxf(feat[n][r], vv);
          }
      }
      lo = nlo; hi = nhi; v8 = nv8;
    }
#pragma unroll
    for (int n = 0; n < 4; ++n) {
      float m = fmaxf(fmaxf(feat[n][0], feat[n][1]), fmaxf(feat[n][2], feat[n][3]));
      m = fmaxf(m, __shfl_xor(m, 16));
      m = fmaxf(m, __shfl_xor(m, 32));
      fsum[n] += m;
    }
  }
  if (g == 0) {
#pragma unroll
    for (int n = 0; n < 4; ++n) redf[wv][s + 16 * n] = fsum[n];
  }
  if (lane == 0) redc[wv] = cnt;
  __syncthreads();
  if (tid < 64) {
    float tot = redf[0][tid] + redf[1][tid] + redf[2][tid] + redf[3][tid];
    partial[blockIdx.x * 64 + tid] = tot;
    if (tid == 0) pcnt[blockIdx.x] = redc[0] + redc[1] + redc[2] + redc[3];
  }
}

// ---------------------------------------------------------------------------
// Per-batch case-grid conv over LDS, PACKED weights, one nt per wave,
// MTW m-tiles in registers (weights stream ONCE per wave). Padded strides
// LDI/LDO break LDS bank alignment. MC = output position count (constexpr).
// ---------------------------------------------------------------------------
template <int CI, int CO, int H, int EIN, bool POOL, bool HAS_BN, bool OUT_F32,
          int LDI, int LDO, int MTW, int MC>
__device__ __forceinline__ void caseconvL(
    int wv, int lane, const __bf16* __restrict__ xin,
    const __bf16* __restrict__ wp,
    const float* __restrict__ cb, const float* __restrict__ cs,
    const float* __restrict__ ct,
    __bf16* __restrict__ yout, float* __restrict__ yf32,
    const __bf16* __restrict__ zpad, int m0)
{
  constexpr int EV   = POOL ? (EIN + 1) / 2 : EIN;
  constexpr int EOUT = EV + 1;
  constexpr int NBI  = 2 * EIN + 1;
  constexpr int HX   = POOL ? 2 * H : H;
  constexpr int NBO  = 2 * EOUT + 1;
  constexpr int NT   = CO / 16;
  constexpr int KC   = CI / 32;
  constexpr int MT   = (MC + 31) / 32;
  constexpr int NP   = POOL ? 4 : 1;
  const int s = lane & 15, g = lane >> 4;
  const int nt = wv % NT;
  const int mg = wv / NT;

  int reph[MTW][2], repw[MTW][2];
  bool act[MTW];
#pragma unroll
  for (int i = 0; i < MTW; ++i) {
    int mt = mg * MTW + i;
    act[i] = (mt < MT);
    int mtc = act[i] ? mt : 0;
#pragma unroll
    for (int mf = 0; mf < 2; ++mf) {
      int m = m0 + mtc * 32 + mf * 16 + s;
      if (m >= m0 + MC) m = m0 + MC - 1;
      int bh = m / NBO, bw = m % NBO;
      reph[i][mf] = repof(bh, H, EOUT);
      repw[i][mf] = repof(bw, H, EOUT);
    }
  }

  f32x4 acc[MTW][2];
#pragma unroll
  for (int i = 0; i < MTW; ++i) {
    acc[i][0] = (f32x4){0.f, 0.f, 0.f, 0.f};
    acc[i][1] = (f32x4){0.f, 0.f, 0.f, 0.f};
  }

#pragma unroll
  for (int tap = 0; tap < 9; ++tap) {
    const int dh = tap / 3, dw = tap % 3;
    const __bf16* base[MTW][2][NP];
#pragma unroll
    for (int i = 0; i < MTW; ++i)
#pragma unroll
      for (int mf = 0; mf < 2; ++mf) {
        int vh = reph[i][mf] + dh - 1, vw = repw[i][mf] + dw - 1;
        if constexpr (POOL) {
          bool valid = (vh >= 0) && (vh < H) && (vw >= 0) && (vw < H);
          int h0 = 0, h1 = 0, w0 = 0, w1 = 0;
          if (valid) {
            h0 = caseof(2 * vh, HX, EIN); h1 = caseof(2 * vh + 1, HX, EIN);
            w0 = caseof(2 * vw, HX, EIN); w1 = caseof(2 * vw + 1, HX, EIN);
          }
          base[i][mf][0] = valid ? xin + (size_t)(h0 * NBI + w0) * LDI : zpad;
          base[i][mf][1] = valid ? xin + (size_t)(h0 * NBI + w1) * LDI : zpad;
          base[i][mf][2] = valid ? xin + (size_t)(h1 * NBI + w0) * LDI : zpad;
          base[i][mf][3] = valid ? xin + (size_t)(h1 * NBI + w1) * LDI : zpad;
        } else {
          int jh = caseof(vh, H, EIN), jw = caseof(vw, H, EIN);
          bool v = (jh >= 0) && (jw >= 0);
          base[i][mf][0] = v ? xin + (size_t)(jh * NBI + jw) * LDI : zpad;
        }
      }
    const __bf16* wrow = wp + (((size_t)tap * NT + nt) * KC) * 512 + lane * 8;
#pragma unroll
    for (int ck = 0; ck < KC; ++ck) {
      vbf8 bb = *(const vbf8*)(wrow + (size_t)ck * 512);
#pragma unroll
      for (int i = 0; i < MTW; ++i) {
        if (!act[i]) continue;
#pragma unroll
        for (int mf = 0; mf < 2; ++mf) {
          vbf8 a;
          if constexpr (POOL) {
            a = max8(max8(*(const vbf8*)(base[i][mf][0] + ck * 32 + 8 * g),
                          *(const vbf8*)(base[i][mf][1] + ck * 32 + 8 * g)),
                     max8(*(const vbf8*)(base[i][mf][2] + ck * 32 + 8 * g),
                          *(const vbf8*)(base[i][mf][3] + ck * 32 + 8 * g)));
          } else {
            a = *(const vbf8*)(base[i][mf][0] + ck * 32 + 8 * g);
          }
          acc[i][mf] = __builtin_amdgcn_mfma_f32_16x16x32_bf16(a, bb, acc[i][mf], 0, 0, 0);
        }
      }
    }
  }

  int co = nt * 16 + s;
  float sc, sh;
  if (HAS_BN) { sc = cs[co]; sh = fmaf(cb[co], sc, ct[co]); }
  else        { sc = 1.f;    sh = cb[co]; }
#pragma unroll
  for (int i = 0; i < MTW; ++i) {
    if (!act[i]) continue;
    int mt = mg * MTW + i;
#pragma unroll
    for (int mf = 0; mf < 2; ++mf) {
#pragma unroll
      for (int r = 0; r < 4; ++r) {
        int m = m0 + mt * 32 + mf * 16 + 4 * g + r;
        if (m < m0 + MC) {
          float v = fmaxf(fmaf(acc[i][mf][r], sc, sh), 0.f);
          if constexpr (OUT_F32) yf32[(size_t)(m - m0) * LDO + co] = v;
          else                   yout[(size_t)m * LDO + co] = (__bf16)v;
        }
      }
    }
  }
}

// ---------------------------------------------------------------------------
// backbone: 4 blocks (one batch each), entire conv chain in LDS; only
// __syncthreads between layers — zero cross-block dependencies.
// ---------------------------------------------------------------------------
__global__ __launch_bounds__(1024) void backbone_kernel(
    const float* __restrict__ ppart, const int* __restrict__ pcnt,
    const __bf16* wt1, const __bf16* wt2, const __bf16* wt3, const __bf16* wt4,
    const __bf16* wt5, const __bf16* wt6, const __bf16* wth,
    const float* cb1, const float* cs1, const float* ct1,
    const float* cb2, const float* cs2, const float* ct2,
    const float* cb3, const float* cs3, const float* ct3,
    const float* cb4, const float* cs4, const float* ct4,
    const float* cb5, const float* cs5, const float* ct5,
    const float* cb6, const float* cs6, const float* ct6,
    const float* hb1, const float* hk2, const float* hb2,
    float* __restrict__ out)
{
  __shared__ float Af[64 * 260];            // 66,560 B (X1/X3/X5 bf16; head f32)
  __shared__ __bf16 Bb[81 * 264];           // 42,768 B (X2/X4/X6; int scratch)
  __shared__ __bf16 X0l[64];
  __shared__ __bf16 zpad[256];
  const int tid = threadIdx.x;
  const int wv = tid >> 6, lane = tid & 63;
  const int b = blockIdx.x;

  // ---- mean of valid pillar features -> X0l ----
  {
    int c = tid & 63, q = tid >> 6;
    float sum = 0.f;
    for (int w = q; w < 1500; w += 16) sum += ppart[(b * 1500 + w) * 64 + c];
    int cl = 0;
    for (int w = tid; w < 1500; w += 1024) cl += pcnt[b * 1500 + w];
    Af[tid] = sum;
    int* shi = (int*)Bb;
    shi[tid] = cl;
    __syncthreads();
    for (int o = 512; o > 0; o >>= 1) {
      if (tid < o) shi[tid] += shi[tid + o];
      __syncthreads();
    }
    if (tid < 64) {
      float tot = 0.f;
#pragma unroll
      for (int q2 = 0; q2 < 16; ++q2) tot += Af[q2 * 64 + tid];
      X0l[tid] = (__bf16)(tot / (float)(shi[0] > 0 ? shi[0] : 1));
    }
    if (tid < 256) zpad[tid] = (__bf16)0.f;
    __syncthreads();
  }
  __bf16* A16 = (__bf16*)Af;

  // c1: X0l -> A16 (X1: 3x3, M=9, LD 72)
  caseconvL<64, 64, 64, 0, false, true, false, 64, 72, 1, 9>(
      wv, lane, X0l, wt1, cb1, cs1, ct1, A16, nullptr, zpad, 0);
  __syncthreads();
  // c2: A16 -> Bb (X2: 5x5, M=25, LD 72)
  caseconvL<64, 64, 64, 1, false, true, false, 72, 72, 1, 25>(
      wv, lane, A16, wt2, cb2, cs2, ct2, Bb, nullptr, zpad, 0);
  __syncthreads();
  // c3 (+pool): Bb -> A16 (X3: 5x5, M=25, CO=128, LD 136)
  caseconvL<64, 128, 32, 2, true, true, false, 72, 136, 1, 25>(
      wv, lane, Bb, wt3, cb3, cs3, ct3, A16, nullptr, zpad, 0);
  __syncthreads();
  // c4: A16 -> Bb (X4: 7x7, M=49, LD 136)
  caseconvL<128, 128, 32, 2, false, true, false, 136, 136, 1, 49>(
      wv, lane, A16, wt4, cb4, cs4, ct4, Bb, nullptr, zpad, 0);
  __syncthreads();
  // c5 (+pool): Bb -> A16 (X5: 7x7, M=49, CO=256, LD 264)
  caseconvL<128, 256, 16, 3, true, true, false, 136, 264, 2, 49>(
      wv, lane, Bb, wt5, cb5, cs5, ct5, A16, nullptr, zpad, 0);
  __syncthreads();
  // c6: A16 -> Bb (X6: 9x9, M=81, LD 264)
  caseconvL<256, 256, 16, 3, false, true, false, 264, 264, 3, 81>(
      wv, lane, A16, wt6, cb6, cs6, ct6, Bb, nullptr, zpad, 0);
  __syncthreads();

  // head conv (11x11, M=121) in f32 chunks (LD 260) + fused 1x1 head + scatter
#pragma unroll
  for (int chunk = 0; chunk < 2; ++chunk) {
    int m0 = chunk * 64;
    int mc = chunk ? 57 : 64;
    if (chunk == 0)
      caseconvL<256, 256, 16, 4, false, false, true, 264, 260, 2, 64>(
          wv, lane, Bb, wth, hb1, nullptr, nullptr, nullptr, Af, zpad, 0);
    else
      caseconvL<256, 256, 16, 4, false, false, true, 264, 260, 2, 57>(
          wv, lane, Bb, wth, hb1, nullptr, nullptr, nullptr, Af, zpad, 64);
    __syncthreads();
    for (int t = tid; t < 8370; t += 1024) {
      int ch = t / 837, rc = t % 837;
      int r = rc / 31, c = rc % 31;
      int rr = (r <= 7) ? r : ((r >= 20) ? r - 11 : 7);
      int cc = (c <= 7) ? c : ((c >= 24) ? c - 15 : 7);
      int ph = caseof(rr, 16, 5), pw = caseof(cc, 16, 5);
      int m = ph * 11 + pw;
      if (m >= m0 && m < m0 + mc) {
        const float* xr = Af + (size_t)(m - m0) * 260;
        float a0 = 0.f, a1 = 0.f, a2 = 0.f, a3 = 0.f;
#pragma unroll 4
        for (int ci = 0; ci < 256; ci += 4) {
          float4 in4 = *(const float4*)(xr + ci);
          a0 = fmaf(in4.x, hk2[(ci + 0) * 10 + ch], a0);
          a1 = fmaf(in4.y, hk2[(ci + 1) * 10 + ch], a1);
          a2 = fmaf(in4.z, hk2[(ci + 2) * 10 + ch], a2);
          a3 = fmaf(in4.w, hk2[(ci + 3) * 10 + ch], a3);
        }
        out[((size_t)(b * 10 + ch) * 27 + r) * 31 + c] =
            (a0 + a1) + (a2 + a3) + hb2[ch];
      }
    }
    __syncthreads();
  }
}

// ---------------------------------------------------------------------------
extern "C" void kernel_launch(void* const* d_in, const int* in_sizes, int n_in,
                              void* d_out, int out_size, void* d_ws, size_t ws_size,
                              hipStream_t stream) {
  (void)in_sizes; (void)n_in; (void)out_size; (void)ws_size;
  const float* pillars = (const float*)d_in[0];
  const float* w1 = (const float*)d_in[1];
  const float* b1 = (const float*)d_in[2];
  const float* s1 = (const float*)d_in[3];
  const float* t1 = (const float*)d_in[4];
  const float* w2 = (const float*)d_in[5];
  const float* b2 = (const float*)d_in[6];
  const float* s2 = (const float*)d_in[7];
  const float* t2 = (const float*)d_in[8];
  const float* ck[6], *cbv[6], *csv[6], *ctv[6];
  for (int i = 0; i < 6; ++i) {
    ck[i]  = (const float*)d_in[9 + i * 4];
    cbv[i] = (const float*)d_in[10 + i * 4];
    csv[i] = (const float*)d_in[11 + i * 4];
    ctv[i] = (const float*)d_in[12 + i * 4];
  }
  const float* hk1 = (const float*)d_in[33];
  const float* hb1 = (const float*)d_in[34];
  const float* hk2 = (const float*)d_in[35];
  const float* hb2 = (const float*)d_in[36];
  const int* num_points = (const int*)d_in[37];
  float* out = (float*)d_out;

  // ---- ws layout ----
  char* wsb = (char*)d_ws;
  size_t off = 0;
  auto alloc = [&](size_t n) { char* p = wsb + off; off = (off + n + 255) & ~(size_t)255; return p; };
  float*  ppart = (float*)alloc(1536000);
  int*    pcnt  = (int*)alloc(24000);
  __bf16* wT    = (__bf16*)alloc(3538944);

  __bf16* wt1 = wT + 0;       __bf16* wt2 = wT + 36864;
  __bf16* wt3 = wT + 73728;   __bf16* wt4 = wT + 147456;
  __bf16* wt5 = wT + 294912;  __bf16* wt6 = wT + 589824;
  __bf16* wth = wT + 1179648;

  pillar_kernel<<<6000, 256, 0, stream>>>(
      pillars, num_points, w1, b1, s1, t1, w2, b2, s2, t2,
      ck[0], ck[1], ck[2], ck[3], ck[4], ck[5], hk1, wT, ppart, pcnt);
  backbone_kernel<<<4, 1024, 0, stream>>>(
      ppart, pcnt, wt1, wt2, wt3, wt4, wt5, wt6, wth,
      cbv[0], csv[0], ctv[0], cbv[1], csv[1], ctv[1],
      cbv[2], csv[2], ctv[2], cbv[3], csv[3], ctv[3],
      cbv[4], csv[4], ctv[4], cbv[5], csv[5], ctv[5],
      hb1, hk2, hb2, out);
}

// Round 14
// 455.689 us; speedup vs baseline: 1.7833x; 1.0751x over previous
//
#include <hip/hip_runtime.h>

// ---------- types ----------
typedef __bf16 vbf8 __attribute__((ext_vector_type(8)));
typedef unsigned short us8 __attribute__((ext_vector_type(8)));
typedef float f32x4 __attribute__((ext_vector_type(4)));
typedef float f32x4u __attribute__((ext_vector_type(4), aligned(4)));

// ---------- band-case helpers ----------
__device__ __forceinline__ int caseof(int h, int H, int e) {
  if (h < 0 || h >= H) return -1;           // EDGE
  if (h < e) return h;
  if (h >= H - e) return h - (H - 1) + 2 * e;
  return e;
}
__device__ __forceinline__ int repof(int i, int H, int eo) {
  return (i <= eo) ? i : H - 1 - 2 * eo + i;
}

__device__ __forceinline__ vbf8 max8(vbf8 a, vbf8 b) {
  us8 ua = __builtin_bit_cast(us8, a), ub = __builtin_bit_cast(us8, b);
  us8 o;
#pragma unroll
  for (int e = 0; e < 8; ++e) o[e] = ua[e] > ub[e] ? ua[e] : ub[e];
  return __builtin_bit_cast(vbf8, o);
}

// ---------------------------------------------------------------------------
// pillar + convw kernel. Blocks 0..431 transpose+PACK conv weights into MFMA
// fragment order: wP[tap][nt][ck][lane][8] bf16. All blocks then run the
// pillar feature net. (Unchanged from R13 — known-good ~106 us.)
// ---------------------------------------------------------------------------
__global__ __launch_bounds__(256) void pillar_kernel(
    const float* __restrict__ pil, const int* __restrict__ npt,
    const float* __restrict__ w1, const float* __restrict__ b1,
    const float* __restrict__ s1, const float* __restrict__ t1,
    const float* __restrict__ w2, const float* __restrict__ b2,
    const float* __restrict__ s2, const float* __restrict__ t2,
    const float* __restrict__ k1, const float* __restrict__ k2,
    const float* __restrict__ k3, const float* __restrict__ k4,
    const float* __restrict__ k5, const float* __restrict__ k6,
    const float* __restrict__ kh, __bf16* __restrict__ wT,
    float* __restrict__ partial, int* __restrict__ pcnt)
{
  __shared__ float tile[64][65];
  __shared__ float redf[4][64];
  __shared__ int redc[4];
  const int tid = threadIdx.x;
  const int wv = tid >> 6, lane = tid & 63;
  const int s = lane & 15, g = lane >> 4;

  if (blockIdx.x < 432) {
    const int tCI[7]    = {64, 64, 64, 128, 128, 256, 256};
    const int tCO[7]    = {64, 64, 128, 128, 256, 256, 256};
    const int tOFF[7]   = {0, 36864, 73728, 147456, 294912, 589824, 1179648};
    const int tTILES[7] = {9, 9, 18, 36, 72, 144, 144};
    int bid = blockIdx.x;
    int ti = 0, acc = 0;
    while (ti < 6 && bid >= acc + tTILES[ti]) { acc += tTILES[ti]; ++ti; }
    int lt = bid - acc;
    int CI = tCI[ti], CO = tCO[ti];
    const float* src;
    if (ti == 0) src = k1; else if (ti == 1) src = k2; else if (ti == 2) src = k3;
    else if (ti == 3) src = k4; else if (ti == 4) src = k5; else if (ti == 5) src = k6;
    else src = kh;
    int cot = CO / 64, tpt = (CI / 64) * cot;
    int tap = lt / tpt; int r2 = lt - tap * tpt;
    int ci0 = (r2 / cot) * 64, co0 = (r2 % cot) * 64;
    const float* sp = src + (size_t)(tap * CI + ci0) * CO + co0;
    int lr = tid >> 6, lc = tid & 63;
#pragma unroll
    for (int rr = 0; rr < 64; rr += 4)
      tile[rr + lr][lc] = sp[(size_t)(rr + lr) * CO + lc];
    __syncthreads();
    __bf16* dstL = wT + tOFF[ti];
    int NT = CO >> 4, KCw = CI >> 5;
#pragma unroll
    for (int rr = 0; rr < 64; rr += 4) {
      int co = co0 + rr + lr;
      int ci = ci0 + lc;
      int nt = co >> 4, ss = co & 15;
      int ck = ci >> 5, gg = (ci >> 3) & 3, ee = ci & 7;
      size_t off = ((((size_t)tap * NT + nt) * KCw + ck) * 64 + gg * 16 + ss) * 8 + ee;
      dstL[off] = (__bf16)tile[lc][rr + lr];
    }
  }

  // ---- inline pillar weight-fragment setup ----
  vbf8 w1f[4], w2f0[4], w2f1[4];
  float be2[4];
#pragma unroll
  for (int m = 0; m < 4; ++m) {
    int c = 32 * (m & 1) + 8 * (s >> 2) + 4 * (m >> 1) + (s & 3);
#pragma unroll
    for (int e = 0; e < 8; ++e) {
      int k = g * 8 + e;
      float v = 0.f;
      if (k < 9)       v = w1[k * 64 + c] * s1[c];
      else if (k == 9) v = fmaf(b1[c], s1[c], t1[c]);
      w1f[m][e] = (__bf16)v;
    }
    int co = s + 16 * m;
#pragma unroll
    for (int e = 0; e < 8; ++e) {
      int k = g * 8 + e;
      w2f0[m][e] = (__bf16)(w2[k * 64 + co] * s2[co]);
      w2f1[m][e] = (__bf16)(w2[(32 + k) * 64 + co] * s2[co]);
    }
    be2[m] = fmaf(b2[co], s2[co], t2[co]);
  }

  const int wid = blockIdx.x * 4 + wv;       // 0..23999
  const int b = wid / 6000;
  const int p0 = (wid - b * 6000) * 2;

  float fsum[4] = {0.f, 0.f, 0.f, 0.f};
  int cnt = 0;

  for (int i = 0; i < 2; ++i) {
    int pidx = b * 12000 + p0 + i;
    int np = npt[pidx];
    if (np <= 0) continue;     // wave-uniform
    ++cnt;
    float feat[4][4];
#pragma unroll
    for (int n = 0; n < 4; ++n)
#pragma unroll
      for (int r = 0; r < 4; ++r) feat[n][r] = 0.f;

    int ngrp = (np + 15) >> 4;
    const float* pbase = pil + (size_t)pidx * 900;
    const float* pp0 = pbase + s * 9;
    f32x4u lo = *(const f32x4u*)pp0;
    f32x4u hi = *(const f32x4u*)(pp0 + 4);
    float v8 = pp0[8];
    for (int grp = 0; grp < ngrp; ++grp) {
      int g2 = min(grp + 1, ngrp - 1);
      int ptn = min(g2 * 16 + s, 99);
      const float* ppn = pbase + ptn * 9;
      f32x4u nlo = *(const f32x4u*)ppn;
      f32x4u nhi = *(const f32x4u*)(ppn + 4);
      float nv8 = ppn[8];

      vbf8 b1f;
      b1f[0] = (__bf16)(g == 0 ? lo[0] : (g == 1 ? v8 : 0.f));
      b1f[1] = (__bf16)(g == 0 ? lo[1] : (g == 1 ? 1.0f : 0.f));
      b1f[2] = (__bf16)(g == 0 ? lo[2] : 0.f);
      b1f[3] = (__bf16)(g == 0 ? lo[3] : 0.f);
      b1f[4] = (__bf16)(g == 0 ? hi[0] : 0.f);
      b1f[5] = (__bf16)(g == 0 ? hi[1] : 0.f);
      b1f[6] = (__bf16)(g == 0 ? hi[2] : 0.f);
      b1f[7] = (__bf16)(g == 0 ? hi[3] : 0.f);

      const f32x4 z = {0.f, 0.f, 0.f, 0.f};
      f32x4 d1[4];
#pragma unroll
      for (int m = 0; m < 4; ++m)
        d1[m] = __builtin_amdgcn_mfma_f32_16x16x32_bf16(w1f[m], b1f, z, 0, 0, 0);

      vbf8 a2f0, a2f1;
#pragma unroll
      for (int r = 0; r < 4; ++r) {
        a2f0[r]     = (__bf16)fmaxf(d1[0][r], 0.f);
        a2f1[r]     = (__bf16)fmaxf(d1[1][r], 0.f);
        a2f0[4 + r] = (__bf16)fmaxf(d1[2][r], 0.f);
        a2f1[4 + r] = (__bf16)fmaxf(d1[3][r], 0.f);
      }

      f32x4 d2[4];
#pragma unroll
      for (int n = 0; n < 4; ++n) {
        f32x4 cb = {be2[n], be2[n], be2[n], be2[n]};
        d2[n] = __builtin_amdgcn_mfma_f32_16x16x32_bf16(a2f0, w2f0[n], cb, 0, 0, 0);
        d2[n] = __builtin_amdgcn_mfma_f32_16x16x32_bf16(a2f1, w2f1[n], d2[n], 0, 0, 0);
      }
      if (((grp + 1) << 4) <= np) {
#pragma unroll
        for (int n = 0; n < 4; ++n)
#pragma unroll
          for (int r = 0; r < 4; ++r) feat[n][r] = fmaxf(feat[n][r], d2[n][r]);
      } else {
#pragma unroll
        for (int n = 0; n < 4; ++n)
#pragma unroll
          for (int r = 0; r < 4; ++r) {
            float vv = (grp * 16 + 4 * g + r < np) ? d2[n][r] : 0.f;
            feat[n][r] = fmaxf(feat[n][r], vv);
          }
      }
      lo = nlo; hi = nhi; v8 = nv8;
    }
#pragma unroll
    for (int n = 0; n < 4; ++n) {
      float m = fmaxf(fmaxf(feat[n][0], feat[n][1]), fmaxf(feat[n][2], feat[n][3]));
      m = fmaxf(m, __shfl_xor(m, 16));
      m = fmaxf(m, __shfl_xor(m, 32));
      fsum[n] += m;
    }
  }
  if (g == 0) {
#pragma unroll
    for (int n = 0; n < 4; ++n) redf[wv][s + 16 * n] = fsum[n];
  }
  if (lane == 0) redc[wv] = cnt;
  __syncthreads();
  if (tid < 64) {
    float tot = redf[0][tid] + redf[1][tid] + redf[2][tid] + redf[3][tid];
    partial[blockIdx.x * 64 + tid] = tot;
    if (tid == 0) pcnt[blockIdx.x] = redc[0] + redc[1] + redc[2] + redc[3];
  }
}

// ---------------------------------------------------------------------------
// Per-batch case-grid conv over LDS, PACKED weights, one nt per wave,
// MTW m-tiles in registers. Weight stream double-buffered in KB-fragment
// batches (KB independent loads in flight while current batch computes).
// ---------------------------------------------------------------------------
template <int CI, int CO, int H, int EIN, bool POOL, bool HAS_BN, bool OUT_F32,
          int LDI, int LDO, int MTW, int MC>
__device__ __forceinline__ void caseconvL(
    int wv, int lane, const __bf16* __restrict__ xin,
    const __bf16* __restrict__ wp,
    const float* __restrict__ cb, const float* __restrict__ cs,
    const float* __restrict__ ct,
    __bf16* __restrict__ yout, float* __restrict__ yf32,
    const __bf16* __restrict__ zpad, int m0)
{
  constexpr int EV   = POOL ? (EIN + 1) / 2 : EIN;
  constexpr int EOUT = EV + 1;
  constexpr int NBI  = 2 * EIN + 1;
  constexpr int HX   = POOL ? 2 * H : H;
  constexpr int NBO  = 2 * EOUT + 1;
  constexpr int NT   = CO / 16;
  constexpr int KC   = CI / 32;
  constexpr int MT   = (MC + 31) / 32;
  constexpr int NP   = POOL ? 4 : 1;
  constexpr int KB   = (KC >= 4) ? 4 : KC;   // weight-load batch size
  constexpr int NB   = KC / KB;              // batches per tap
  constexpr int TB   = 9 * NB;               // total steps
  const int s = lane & 15, g = lane >> 4;
  const int nt = wv % NT;
  const int mg = wv / NT;

  int reph[MTW][2], repw[MTW][2];
  bool act[MTW];
#pragma unroll
  for (int i = 0; i < MTW; ++i) {
    int mt = mg * MTW + i;
    act[i] = (mt < MT);
    int mtc = act[i] ? mt : 0;
#pragma unroll
    for (int mf = 0; mf < 2; ++mf) {
      int m = m0 + mtc * 32 + mf * 16 + s;
      if (m >= m0 + MC) m = m0 + MC - 1;
      int bh = m / NBO, bw = m % NBO;
      reph[i][mf] = repof(bh, H, EOUT);
      repw[i][mf] = repof(bw, H, EOUT);
    }
  }

  f32x4 acc[MTW][2];
#pragma unroll
  for (int i = 0; i < MTW; ++i) {
    acc[i][0] = (f32x4){0.f, 0.f, 0.f, 0.f};
    acc[i][1] = (f32x4){0.f, 0.f, 0.f, 0.f};
  }

  const __bf16* base[MTW][2][NP];
  vbf8 wf[2][KB];
  // preload step 0 (tap 0, ck 0..KB-1)
#pragma unroll
  for (int k = 0; k < KB; ++k)
    wf[0][k] = *(const vbf8*)(wp + (((size_t)0 * NT + nt) * KC + k) * 512 + lane * 8);

#pragma unroll
  for (int idx = 0; idx < TB; ++idx) {
    const int cur = idx & 1;
    const int tap = idx / NB, bat = idx % NB;
    if (bat == 0) {
      const int dh = tap / 3, dw = tap % 3;
#pragma unroll
      for (int i = 0; i < MTW; ++i)
#pragma unroll
        for (int mf = 0; mf < 2; ++mf) {
          int vh = reph[i][mf] + dh - 1, vw = repw[i][mf] + dw - 1;
          if constexpr (POOL) {
            bool valid = (vh >= 0) && (vh < H) && (vw >= 0) && (vw < H);
            int h0 = 0, h1 = 0, w0 = 0, w1 = 0;
            if (valid) {
              h0 = caseof(2 * vh, HX, EIN); h1 = caseof(2 * vh + 1, HX, EIN);
              w0 = caseof(2 * vw, HX, EIN); w1 = caseof(2 * vw + 1, HX, EIN);
            }
            base[i][mf][0] = valid ? xin + (size_t)(h0 * NBI + w0) * LDI : zpad;
            base[i][mf][1] = valid ? xin + (size_t)(h0 * NBI + w1) * LDI : zpad;
            base[i][mf][2] = valid ? xin + (size_t)(h1 * NBI + w0) * LDI : zpad;
            base[i][mf][3] = valid ? xin + (size_t)(h1 * NBI + w1) * LDI : zpad;
          } else {
            int jh = caseof(vh, H, EIN), jw = caseof(vw, H, EIN);
            bool v = (jh >= 0) && (jw >= 0);
            base[i][mf][0] = v ? xin + (size_t)(jh * NBI + jw) * LDI : zpad;
          }
        }
    }
    if (idx + 1 < TB) {
      const int tapn = (idx + 1) / NB, batn = (idx + 1) % NB;
#pragma unroll
      for (int k = 0; k < KB; ++k)
        wf[cur ^ 1][k] = *(const vbf8*)(
            wp + (((size_t)tapn * NT + nt) * KC + batn * KB + k) * 512 + lane * 8);
    }
#pragma unroll
    for (int k = 0; k < KB; ++k) {
      const int ck = bat * KB + k;
#pragma unroll
      for (int i = 0; i < MTW; ++i) {
        if (!act[i]) continue;
#pragma unroll
        for (int mf = 0; mf < 2; ++mf) {
          vbf8 a;
          if constexpr (POOL) {
            a = max8(max8(*(const vbf8*)(base[i][mf][0] + ck * 32 + 8 * g),
                          *(const vbf8*)(base[i][mf][1] + ck * 32 + 8 * g)),
                     max8(*(const vbf8*)(base[i][mf][2] + ck * 32 + 8 * g),
                          *(const vbf8*)(base[i][mf][3] + ck * 32 + 8 * g)));
          } else {
            a = *(const vbf8*)(base[i][mf][0] + ck * 32 + 8 * g);
          }
          acc[i][mf] = __builtin_amdgcn_mfma_f32_16x16x32_bf16(a, wf[cur][k], acc[i][mf], 0, 0, 0);
        }
      }
    }
  }

  int co = nt * 16 + s;
  float sc, sh;
  if (HAS_BN) { sc = cs[co]; sh = fmaf(cb[co], sc, ct[co]); }
  else        { sc = 1.f;    sh = cb[co]; }
#pragma unroll
  for (int i = 0; i < MTW; ++i) {
    if (!act[i]) continue;
    int mt = mg * MTW + i;
#pragma unroll
    for (int mf = 0; mf < 2; ++mf) {
#pragma unroll
      for (int r = 0; r < 4; ++r) {
        int m = m0 + mt * 32 + mf * 16 + 4 * g + r;
        if (m < m0 + MC) {
          float v = fmaxf(fmaf(acc[i][mf][r], sc, sh), 0.f);
          if constexpr (OUT_F32) yf32[(size_t)(m - m0) * LDO + co] = v;
          else                   yout[(size_t)m * LDO + co] = (__bf16)v;
        }
      }
    }
  }
}

// ---------------------------------------------------------------------------
// backbone: 4 blocks (one batch each), entire conv chain in LDS; only
// __syncthreads between layers — zero cross-block dependencies.
// ---------------------------------------------------------------------------
__global__ __launch_bounds__(1024) void backbone_kernel(
    const float* __restrict__ ppart, const int* __restrict__ pcnt,
    const __bf16* wt1, const __bf16* wt2, const __bf16* wt3, const __bf16* wt4,
    const __bf16* wt5, const __bf16* wt6, const __bf16* wth,
    const float* cb1, const float* cs1, const float* ct1,
    const float* cb2, const float* cs2, const float* ct2,
    const float* cb3, const float* cs3, const float* ct3,
    const float* cb4, const float* cs4, const float* ct4,
    const float* cb5, const float* cs5, const float* ct5,
    const float* cb6, const float* cs6, const float* ct6,
    const float* hb1, const float* hk2, const float* hb2,
    float* __restrict__ out)
{
  __shared__ float Af[64 * 260];            // 66,560 B (X1/X3/X5 bf16; head f32)
  __shared__ __bf16 Bb[81 * 264];           // 42,768 B (X2/X4/X6; int scratch)
  __shared__ __bf16 X0l[64];
  __shared__ __bf16 zpad[256];
  const int tid = threadIdx.x;
  const int wv = tid >> 6, lane = tid & 63;
  const int b = blockIdx.x;

  // ---- mean of valid pillar features -> X0l (float4-vectorized) ----
  {
    f32x4* vec = (f32x4*)Af;
    int c4 = tid & 15, wr = tid >> 4;       // wr 0..63
    f32x4 sum = {0.f, 0.f, 0.f, 0.f};
    for (int w = wr; w < 1500; w += 64)
      sum += *(const f32x4u*)(ppart + (size_t)(b * 1500 + w) * 64 + c4 * 4);
    vec[wr * 16 + c4] = sum;
    int cl = 0;
    for (int w = tid; w < 1500; w += 1024) cl += pcnt[b * 1500 + w];
    int* shi = (int*)Bb;
    shi[tid] = cl;
    __syncthreads();
    for (int o = 512; o > 0; o >>= 1) {
      if (tid < o) shi[tid] += shi[tid + o];
      __syncthreads();
    }
    for (int o = 32; o > 0; o >>= 1) {
      if (wr < o) vec[wr * 16 + c4] += vec[(wr + o) * 16 + c4];
      __syncthreads();
    }
    if (tid < 16) {
      f32x4 tot = vec[tid];
      float inv = 1.f / (float)(shi[0] > 0 ? shi[0] : 1);
#pragma unroll
      for (int e = 0; e < 4; ++e) X0l[tid * 4 + e] = (__bf16)(tot[e] * inv);
    }
    if (tid < 256) zpad[tid] = (__bf16)0.f;
    __syncthreads();
  }
  __bf16* A16 = (__bf16*)Af;

  // c1: X0l -> A16 (X1: 3x3, M=9, LD 72)
  caseconvL<64, 64, 64, 0, false, true, false, 64, 72, 1, 9>(
      wv, lane, X0l, wt1, cb1, cs1, ct1, A16, nullptr, zpad, 0);
  __syncthreads();
  // c2: A16 -> Bb (X2: 5x5, M=25, LD 72)
  caseconvL<64, 64, 64, 1, false, true, false, 72, 72, 1, 25>(
      wv, lane, A16, wt2, cb2, cs2, ct2, Bb, nullptr, zpad, 0);
  __syncthreads();
  // c3 (+pool): Bb -> A16 (X3: 5x5, M=25, CO=128, LD 136)
  caseconvL<64, 128, 32, 2, true, true, false, 72, 136, 1, 25>(
      wv, lane, Bb, wt3, cb3, cs3, ct3, A16, nullptr, zpad, 0);
  __syncthreads();
  // c4: A16 -> Bb (X4: 7x7, M=49, LD 136)
  caseconvL<128, 128, 32, 2, false, true, false, 136, 136, 1, 49>(
      wv, lane, A16, wt4, cb4, cs4, ct4, Bb, nullptr, zpad, 0);
  __syncthreads();
  // c5 (+pool): Bb -> A16 (X5: 7x7, M=49, CO=256, LD 264)
  caseconvL<128, 256, 16, 3, true, true, false, 136, 264, 2, 49>(
      wv, lane, Bb, wt5, cb5, cs5, ct5, A16, nullptr, zpad, 0);
  __syncthreads();
  // c6: A16 -> Bb (X6: 9x9, M=81, LD 264)
  caseconvL<256, 256, 16, 3, false, true, false, 264, 264, 3, 81>(
      wv, lane, A16, wt6, cb6, cs6, ct6, Bb, nullptr, zpad, 0);
  __syncthreads();

  // head conv (11x11, M=121) in f32 chunks (LD 260) + fused 1x1 head + scatter
#pragma unroll
  for (int chunk = 0; chunk < 2; ++chunk) {
    int m0 = chunk * 64;
    int mc = chunk ? 57 : 64;
    if (chunk == 0)
      caseconvL<256, 256, 16, 4, false, false, true, 264, 260, 2, 64>(
          wv, lane, Bb, wth, hb1, nullptr, nullptr, nullptr, Af, zpad, 0);
    else
      caseconvL<256, 256, 16, 4, false, false, true, 264, 260, 2, 57>(
          wv, lane, Bb, wth, hb1, nullptr, nullptr, nullptr, Af, zpad, 64);
    __syncthreads();
    for (int t = tid; t < 8370; t += 1024) {
      int ch = t / 837, rc = t % 837;
      int r = rc / 31, c = rc % 31;
      int rr = (r <= 7) ? r : ((r >= 20) ? r - 11 : 7);
      int cc = (c <= 7) ? c : ((c >= 24) ? c - 15 : 7);
      int ph = caseof(rr, 16, 5), pw = caseof(cc, 16, 5);
      int m = ph * 11 + pw;
      if (m >= m0 && m < m0 + mc) {
        const float* xr = Af + (size_t)(m - m0) * 260;
        float a0 = 0.f, a1 = 0.f, a2 = 0.f, a3 = 0.f;
#pragma unroll 4
        for (int ci = 0; ci < 256; ci += 4) {
          float4 in4 = *(const float4*)(xr + ci);
          a0 = fmaf(in4.x, hk2[(ci + 0) * 10 + ch], a0);
          a1 = fmaf(in4.y, hk2[(ci + 1) * 10 + ch], a1);
          a2 = fmaf(in4.z, hk2[(ci + 2) * 10 + ch], a2);
          a3 = fmaf(in4.w, hk2[(ci + 3) * 10 + ch], a3);
        }
        out[((size_t)(b * 10 + ch) * 27 + r) * 31 + c] =
            (a0 + a1) + (a2 + a3) + hb2[ch];
      }
    }
    __syncthreads();
  }
}

// ---------------------------------------------------------------------------
extern "C" void kernel_launch(void* const* d_in, const int* in_sizes, int n_in,
                              void* d_out, int out_size, void* d_ws, size_t ws_size,
                              hipStream_t stream) {
  (void)in_sizes; (void)n_in; (void)out_size; (void)ws_size;
  const float* pillars = (const float*)d_in[0];
  const float* w1 = (const float*)d_in[1];
  const float* b1 = (const float*)d_in[2];
  const float* s1 = (const float*)d_in[3];
  const float* t1 = (const float*)d_in[4];
  const float* w2 = (const float*)d_in[5];
  const float* b2 = (const float*)d_in[6];
  const float* s2 = (const float*)d_in[7];
  const float* t2 = (const float*)d_in[8];
  const float* ck[6], *cbv[6], *csv[6], *ctv[6];
  for (int i = 0; i < 6; ++i) {
    ck[i]  = (const float*)d_in[9 + i * 4];
    cbv[i] = (const float*)d_in[10 + i * 4];
    csv[i] = (const float*)d_in[11 + i * 4];
    ctv[i] = (const float*)d_in[12 + i * 4];
  }
  const float* hk1 = (const float*)d_in[33];
  const float* hb1 = (const float*)d_in[34];
  const float* hk2 = (const float*)d_in[35];
  const float* hb2 = (const float*)d_in[36];
  const int* num_points = (const int*)d_in[37];
  float* out = (float*)d_out;

  // ---- ws layout ----
  char* wsb = (char*)d_ws;
  size_t off = 0;
  auto alloc = [&](size_t n) { char* p = wsb + off; off = (off + n + 255) & ~(size_t)255; return p; };
  float*  ppart = (float*)alloc(1536000);
  int*    pcnt  = (int*)alloc(24000);
  __bf16* wT    = (__bf16*)alloc(3538944);

  __bf16* wt1 = wT + 0;       __bf16* wt2 = wT + 36864;
  __bf16* wt3 = wT + 73728;   __bf16* wt4 = wT + 147456;
  __bf16* wt5 = wT + 294912;  __bf16* wt6 = wT + 589824;
  __bf16* wth = wT + 1179648;

  pillar_kernel<<<6000, 256, 0, stream>>>(
      pillars, num_points, w1, b1, s1, t1, w2, b2, s2, t2,
      ck[0], ck[1], ck[2], ck[3], ck[4], ck[5], hk1, wT, ppart, pcnt);
  backbone_kernel<<<4, 1024, 0, stream>>>(
      ppart, pcnt, wt1, wt2, wt3, wt4, wt5, wt6, wth,
      cbv[0], csv[0], ctv[0], cbv[1], csv[1], ctv[1],
      cbv[2], csv[2], ctv[2], cbv[3], csv[3], ctv[3],
      cbv[4], csv[4], ctv[4], cbv[5], csv[5], ctv[5],
      hb1, hk2, hb2, out);
}